// Round 1
// baseline (970.774 us; speedup 1.0000x reference)
//
#include <hip/hip_runtime.h>

// GATv2 2-layer encoder, fp32 throughout.
// N=50000 nodes, E=800000 edges, IN=256, H=4 heads, C=64, LAT=32, ED=3.
// Workspace layout (~129.3 MB): xl(51.2M) xr(51.2M) h1(12.8M) deg lsum row_start cursor csr(12.8M)

#define NN  50000
#define EE  800000
#define HC  256     // H*C
#define NSLOPE 0.2f

// ---------------- CSR build ----------------
__global__ __launch_bounds__(256) void deg_kernel(
    const int* __restrict__ ei, const float* __restrict__ ea,
    int* __restrict__ deg, float* __restrict__ lsum)
{
    int e = blockIdx.x * 256 + threadIdx.x;
    if (e >= EE) return;
    int d = ei[EE + e];
    atomicAdd(&deg[d], 1);
    atomicAdd(&lsum[d * 3 + 0], ea[e * 3 + 0]);
    atomicAdd(&lsum[d * 3 + 1], ea[e * 3 + 1]);
    atomicAdd(&lsum[d * 3 + 2], ea[e * 3 + 2]);
}

__global__ __launch_bounds__(1024) void scan_kernel(
    const int* __restrict__ deg, int* __restrict__ row_start, int* __restrict__ cursor)
{
    __shared__ int sums[1024];
    const int tid = threadIdx.x;
    const int CH = (NN + 1023) / 1024;           // 49
    int b = tid * CH, e = min(b + CH, NN);
    int s = 0;
    for (int i = b; i < e; i++) s += deg[i];
    sums[tid] = s;
    __syncthreads();
    for (int off = 1; off < 1024; off <<= 1) {
        int v = (tid >= off) ? sums[tid - off] : 0;
        __syncthreads();
        sums[tid] += v;
        __syncthreads();
    }
    int run = (tid == 0) ? 0 : sums[tid - 1];
    for (int i = b; i < e; i++) {
        row_start[i] = run;
        cursor[i]    = run;
        run += deg[i];
    }
    if (tid == 0) row_start[NN] = EE;
}

__global__ __launch_bounds__(256) void scatter_kernel(
    const int* __restrict__ ei, const float* __restrict__ ea,
    int* __restrict__ cursor, float4* __restrict__ csr)
{
    int e = blockIdx.x * 256 + threadIdx.x;
    if (e >= EE) return;
    int s = ei[e];
    int d = ei[EE + e];
    int pos = atomicAdd(&cursor[d], 1);
    float4 rec;
    rec.x = __int_as_float(s);
    rec.y = ea[e * 3 + 0];
    rec.z = ea[e * 3 + 1];
    rec.w = ea[e * 3 + 2];
    csr[pos] = rec;
}

// ---------------- GEMM: C[M x 256] = A[M x K] @ W[K x 256] + bias ----------------
__global__ __launch_bounds__(256) void gemm_bias_256(
    const float* __restrict__ A, const float* __restrict__ W,
    const float* __restrict__ bias, float* __restrict__ C,
    int M, int K)
{
    __shared__ float As[32][64];   // [k][m] (transposed for b128 fragment reads)
    __shared__ float Bs[32][64];   // [k][n]
    const int tid = threadIdx.x;
    const int bm = blockIdx.y << 6;
    const int bn = blockIdx.x << 6;
    const int tx = tid & 15, ty = tid >> 4;
    float acc[4][4] = {};
    for (int k0 = 0; k0 < K; k0 += 32) {
#pragma unroll
        for (int i = 0; i < 2; i++) {
            int idx = tid + (i << 8);            // 0..511
            int r  = idx >> 3;                   // 0..63
            int c  = (idx & 7) << 2;             // 0..28
            float4 v = make_float4(0.f, 0.f, 0.f, 0.f);
            if (bm + r < M) v = *(const float4*)&A[(size_t)(bm + r) * K + (k0 + c)];
            As[c + 0][r] = v.x; As[c + 1][r] = v.y; As[c + 2][r] = v.z; As[c + 3][r] = v.w;
            int rb = idx >> 4;                   // 0..31
            int cb = (idx & 15) << 2;            // 0..60
            *(float4*)&Bs[rb][cb] = *(const float4*)&W[(size_t)(k0 + rb) * HC + (bn + cb)];
        }
        __syncthreads();
#pragma unroll
        for (int k = 0; k < 32; k++) {
            float4 a = *(const float4*)&As[k][ty << 2];
            float4 b = *(const float4*)&Bs[k][tx << 2];
            float av[4] = {a.x, a.y, a.z, a.w};
            float bv[4] = {b.x, b.y, b.z, b.w};
#pragma unroll
            for (int i = 0; i < 4; i++)
#pragma unroll
                for (int j = 0; j < 4; j++)
                    acc[i][j] = fmaf(av[i], bv[j], acc[i][j]);
        }
        __syncthreads();
    }
    float4 bv = *(const float4*)&bias[bn + (tx << 2)];
#pragma unroll
    for (int i = 0; i < 4; i++) {
        int r = bm + (ty << 2) + i;
        if (r < M) {
            float4 o;
            o.x = acc[i][0] + bv.x;
            o.y = acc[i][1] + bv.y;
            o.z = acc[i][2] + bv.z;
            o.w = acc[i][3] + bv.w;
            *(float4*)&C[(size_t)r * HC + (bn + (tx << 2))] = o;
        }
    }
}

// ---------------- Fused per-node edge attention + aggregation ----------------
// One wave per node. lane = h*16 + q; lane owns channels [4q..4q+3] of head h,
// i.e. flat offset lane*4 into the H*C=256 vector.
__global__ __launch_bounds__(256) void gat_edge(
    const float* __restrict__ xl, const float* __restrict__ xr,
    const float4* __restrict__ csr, const int* __restrict__ row_start,
    const int* __restrict__ deg, const float* __restrict__ lsum,
    const float* __restrict__ att, const float* __restrict__ We,
    const float* __restrict__ bias, float* __restrict__ out)
{
    const int lane = threadIdx.x & 63;
    const int node = (blockIdx.x * 256 + threadIdx.x) >> 6;
    if (node >= NN) return;
    const int j4 = lane << 2;

    const float4 xr4 = *(const float4*)&xr[(size_t)node * HC + j4];
    const float4 at4 = *(const float4*)&att[j4];
    const float4 w0  = *(const float4*)&We[j4];
    const float4 w1  = *(const float4*)&We[HC + j4];
    const float4 w2  = *(const float4*)&We[2 * HC + j4];

    float acc0 = 0.f, acc1 = 0.f, acc2 = 0.f, acc3 = 0.f, denom = 0.f;
    const int beg = row_start[node], end = row_start[node + 1];

    for (int i = beg; i <= end; i++) {
        int s; float ea0, ea1, ea2;
        if (i < end) {
            float4 rec = csr[i];
            s = __float_as_int(rec.x);
            ea0 = rec.y; ea1 = rec.z; ea2 = rec.w;
        } else {
            // self loop: edge_attr = mean of incoming edge_attr (0 if deg==0)
            s = node;
            float rd = 1.0f / fmaxf((float)deg[node], 1.0f);
            ea0 = lsum[node * 3 + 0] * rd;
            ea1 = lsum[node * 3 + 1] * rd;
            ea2 = lsum[node * 3 + 2] * rd;
        }
        float4 xv = *(const float4*)&xl[(size_t)s * HC + j4];
        float m0 = xv.x + xr4.x + ea0 * w0.x + ea1 * w1.x + ea2 * w2.x;
        float m1 = xv.y + xr4.y + ea0 * w0.y + ea1 * w1.y + ea2 * w2.y;
        float m2 = xv.z + xr4.z + ea0 * w0.z + ea1 * w1.z + ea2 * w2.z;
        float m3 = xv.w + xr4.w + ea0 * w0.w + ea1 * w1.w + ea2 * w2.w;
        m0 = (m0 > 0.f) ? m0 : NSLOPE * m0;
        m1 = (m1 > 0.f) ? m1 : NSLOPE * m1;
        m2 = (m2 > 0.f) ? m2 : NSLOPE * m2;
        m3 = (m3 > 0.f) ? m3 : NSLOPE * m3;
        float p = m0 * at4.x + m1 * at4.y + m2 * at4.z + m3 * at4.w;
        // reduce within the 16-lane head group -> alpha[h] broadcast to group
        p += __shfl_xor(p, 1);
        p += __shfl_xor(p, 2);
        p += __shfl_xor(p, 4);
        p += __shfl_xor(p, 8);
        // softmax is shift-invariant; alpha is O(1) so no max subtraction needed
        float ex = expf(p);
        denom += ex;
        acc0 = fmaf(ex, xv.x, acc0);
        acc1 = fmaf(ex, xv.y, acc1);
        acc2 = fmaf(ex, xv.z, acc2);
        acc3 = fmaf(ex, xv.w, acc3);
    }

    const float inv = 1.0f / denom;
    float r0 = acc0 * inv, r1 = acc1 * inv, r2 = acc2 * inv, r3 = acc3 * inv;
    // head mean: lanes l, l+16, l+32, l+48 hold heads 0..3 of the same channels
    r0 += __shfl_xor(r0, 16); r0 += __shfl_xor(r0, 32);
    r1 += __shfl_xor(r1, 16); r1 += __shfl_xor(r1, 32);
    r2 += __shfl_xor(r2, 16); r2 += __shfl_xor(r2, 32);
    r3 += __shfl_xor(r3, 16); r3 += __shfl_xor(r3, 32);
    if (lane < 16) {
        float4 bv = *(const float4*)&bias[j4];
        float4 o;
        o.x = fmaxf(0.25f * r0 + bv.x, 0.f);   // mean over H=4 heads, +bias, ReLU
        o.y = fmaxf(0.25f * r1 + bv.y, 0.f);
        o.z = fmaxf(0.25f * r2 + bv.z, 0.f);
        o.w = fmaxf(0.25f * r3 + bv.w, 0.f);
        *(float4*)&out[(size_t)node * 64 + j4] = o;
    }
}

// ---------------- final linear: out[N x 32] = h[N x 64] @ Wmu + bmu ----------------
__global__ __launch_bounds__(256) void mu_kernel(
    const float* __restrict__ h, const float* __restrict__ Wmu,
    const float* __restrict__ bmu, float* __restrict__ out)
{
    __shared__ float ws[64 * 32];
    __shared__ float hs[8 * 64];
    const int tid = threadIdx.x;
#pragma unroll
    for (int i = 0; i < 8; i++) ws[tid + i * 256] = Wmu[tid + i * 256];
    const int nb = blockIdx.x * 8;   // 8 nodes/block, NN % 8 == 0
    {
        int idx = tid * 2;
        *(float2*)&hs[idx] = *(const float2*)&h[(size_t)nb * 64 + idx];
    }
    __syncthreads();
    const int ln = tid >> 5;     // 0..7
    const int o  = tid & 31;
    float acc = bmu[o];
#pragma unroll
    for (int k = 0; k < 64; k++) acc = fmaf(hs[ln * 64 + k], ws[k * 32 + o], acc);
    out[(size_t)(nb + ln) * 32 + o] = acc;
}

// ---------------- launch ----------------
extern "C" void kernel_launch(void* const* d_in, const int* in_sizes, int n_in,
                              void* d_out, int out_size, void* d_ws, size_t ws_size,
                              hipStream_t stream) {
    const float* x    = (const float*)d_in[0];
    const int*   ei   = (const int*)  d_in[1];
    const float* ea   = (const float*)d_in[2];
    const float* Wl0  = (const float*)d_in[3];
    const float* bl0  = (const float*)d_in[4];
    const float* Wr0  = (const float*)d_in[5];
    const float* br0  = (const float*)d_in[6];
    const float* We0  = (const float*)d_in[7];
    const float* att0 = (const float*)d_in[8];
    const float* bi0  = (const float*)d_in[9];
    const float* Wl1  = (const float*)d_in[10];
    const float* bl1  = (const float*)d_in[11];
    const float* Wr1  = (const float*)d_in[12];
    const float* br1  = (const float*)d_in[13];
    const float* We1  = (const float*)d_in[14];
    const float* att1 = (const float*)d_in[15];
    const float* bi1  = (const float*)d_in[16];
    const float* Wmu  = (const float*)d_in[17];
    const float* bmu  = (const float*)d_in[18];
    float* out = (float*)d_out;

    // workspace carve-up
    float* xl   = (float*)d_ws;                       // NN*256
    float* xr   = xl + (size_t)NN * HC;               // NN*256
    float* h1   = xr + (size_t)NN * HC;               // NN*64
    int*   deg  = (int*)(h1 + (size_t)NN * 64);       // NN
    float* lsum = (float*)(deg + NN);                 // NN*3
    int*   rows = (int*)(lsum + (size_t)NN * 3);      // NN+1
    int*   curs = rows + NN + 1;                      // NN
    uintptr_t p = (uintptr_t)(curs + NN);
    p = (p + 255) & ~(uintptr_t)255;
    float4* csr = (float4*)p;                         // EE records

    // CSR build (edge_index/edge_attr shared by both layers)
    hipMemsetAsync(deg, 0, NN * sizeof(int), stream);
    hipMemsetAsync(lsum, 0, NN * 3 * sizeof(float), stream);
    deg_kernel<<<(EE + 255) / 256, 256, 0, stream>>>(ei, ea, deg, lsum);
    scan_kernel<<<1, 1024, 0, stream>>>(deg, rows, curs);
    scatter_kernel<<<(EE + 255) / 256, 256, 0, stream>>>(ei, ea, curs, csr);

    dim3 gg(4, (NN + 63) / 64);
    const int gat_grid = (NN * 64) / 256;   // one wave per node

    // layer 0
    gemm_bias_256<<<gg, 256, 0, stream>>>(x, Wl0, bl0, xl, NN, 256);
    gemm_bias_256<<<gg, 256, 0, stream>>>(x, Wr0, br0, xr, NN, 256);
    gat_edge<<<gat_grid, 256, 0, stream>>>(xl, xr, csr, rows, deg, lsum, att0, We0, bi0, h1);

    // layer 1 (xl/xr buffers reused)
    gemm_bias_256<<<gg, 256, 0, stream>>>(h1, Wl1, bl1, xl, NN, 64);
    gemm_bias_256<<<gg, 256, 0, stream>>>(h1, Wr1, br1, xr, NN, 64);
    gat_edge<<<gat_grid, 256, 0, stream>>>(xl, xr, csr, rows, deg, lsum, att1, We1, bi1, h1);

    // head
    mu_kernel<<<NN / 8, 256, 0, stream>>>(h1, Wmu, bmu, out);
}

// Round 2
// 841.631 us; speedup vs baseline: 1.1534x; 1.1534x over previous
//
#include <hip/hip_runtime.h>

// GATv2 2-layer encoder, fp32 throughout.
// N=50000 nodes, E=800000 edges, IN=256, H=4 heads, C=64, LAT=32, ED=3.
// R2: deg_kernel stripped to 1 int atomic/edge (loop-attr mean now computed
//     in-register inside gat_edge); vectorized deg/scatter; gat_edge loop
//     restructured (self-loop hoisted, 1-deep prefetch).

#define NN  50000
#define EE  800000
#define HC  256     // H*C
#define NSLOPE 0.2f

// ---------------- CSR build ----------------
__global__ __launch_bounds__(256) void deg_kernel(
    const int* __restrict__ dst, int* __restrict__ deg)
{
    int i = blockIdx.x * 256 + threadIdx.x;      // one int4 (4 edges) per thread
    if (i >= EE / 4) return;
    int4 v = ((const int4*)dst)[i];
    atomicAdd(&deg[v.x], 1);
    atomicAdd(&deg[v.y], 1);
    atomicAdd(&deg[v.z], 1);
    atomicAdd(&deg[v.w], 1);
}

__global__ __launch_bounds__(1024) void scan_kernel(
    const int* __restrict__ deg, int* __restrict__ row_start, int* __restrict__ cursor)
{
    __shared__ int sums[1024];
    const int tid = threadIdx.x;
    const int CH = (NN + 1023) / 1024;           // 49
    int b = tid * CH, e = min(b + CH, NN);
    int s = 0;
    for (int i = b; i < e; i++) s += deg[i];
    sums[tid] = s;
    __syncthreads();
    for (int off = 1; off < 1024; off <<= 1) {
        int v = (tid >= off) ? sums[tid - off] : 0;
        __syncthreads();
        sums[tid] += v;
        __syncthreads();
    }
    int run = (tid == 0) ? 0 : sums[tid - 1];
    for (int i = b; i < e; i++) {
        row_start[i] = run;
        cursor[i]    = run;
        run += deg[i];
    }
    if (tid == 0) row_start[NN] = EE;
}

__global__ __launch_bounds__(256) void scatter_kernel(
    const int* __restrict__ ei, const float* __restrict__ ea,
    int* __restrict__ cursor, float4* __restrict__ csr)
{
    int i = blockIdx.x * 256 + threadIdx.x;      // 4 edges per thread
    if (i >= EE / 4) return;
    int4 s = ((const int4*)ei)[i];
    int4 d = ((const int4*)(ei + EE))[i];
    float4 e0 = ((const float4*)ea)[i * 3 + 0];
    float4 e1 = ((const float4*)ea)[i * 3 + 1];
    float4 e2 = ((const float4*)ea)[i * 3 + 2];
    int p0 = atomicAdd(&cursor[d.x], 1);
    int p1 = atomicAdd(&cursor[d.y], 1);
    int p2 = atomicAdd(&cursor[d.z], 1);
    int p3 = atomicAdd(&cursor[d.w], 1);
    csr[p0] = make_float4(__int_as_float(s.x), e0.x, e0.y, e0.z);
    csr[p1] = make_float4(__int_as_float(s.y), e0.w, e1.x, e1.y);
    csr[p2] = make_float4(__int_as_float(s.z), e1.z, e1.w, e2.x);
    csr[p3] = make_float4(__int_as_float(s.w), e2.y, e2.z, e2.w);
}

// ---------------- GEMM: C[M x 256] = A[M x K] @ W[K x 256] + bias ----------------
__global__ __launch_bounds__(256) void gemm_bias_256(
    const float* __restrict__ A, const float* __restrict__ W,
    const float* __restrict__ bias, float* __restrict__ C,
    int M, int K)
{
    __shared__ float As[32][64];   // [k][m]
    __shared__ float Bs[32][64];   // [k][n]
    const int tid = threadIdx.x;
    const int bm = blockIdx.y << 6;
    const int bn = blockIdx.x << 6;
    const int tx = tid & 15, ty = tid >> 4;
    float acc[4][4] = {};
    for (int k0 = 0; k0 < K; k0 += 32) {
#pragma unroll
        for (int i = 0; i < 2; i++) {
            int idx = tid + (i << 8);            // 0..511
            int r  = idx >> 3;                   // 0..63
            int c  = (idx & 7) << 2;             // 0..28
            float4 v = make_float4(0.f, 0.f, 0.f, 0.f);
            if (bm + r < M) v = *(const float4*)&A[(size_t)(bm + r) * K + (k0 + c)];
            As[c + 0][r] = v.x; As[c + 1][r] = v.y; As[c + 2][r] = v.z; As[c + 3][r] = v.w;
            int rb = idx >> 4;                   // 0..31
            int cb = (idx & 15) << 2;            // 0..60
            *(float4*)&Bs[rb][cb] = *(const float4*)&W[(size_t)(k0 + rb) * HC + (bn + cb)];
        }
        __syncthreads();
#pragma unroll
        for (int k = 0; k < 32; k++) {
            float4 a = *(const float4*)&As[k][ty << 2];
            float4 b = *(const float4*)&Bs[k][tx << 2];
            float av[4] = {a.x, a.y, a.z, a.w};
            float bv[4] = {b.x, b.y, b.z, b.w};
#pragma unroll
            for (int i = 0; i < 4; i++)
#pragma unroll
                for (int j = 0; j < 4; j++)
                    acc[i][j] = fmaf(av[i], bv[j], acc[i][j]);
        }
        __syncthreads();
    }
    float4 bv = *(const float4*)&bias[bn + (tx << 2)];
#pragma unroll
    for (int i = 0; i < 4; i++) {
        int r = bm + (ty << 2) + i;
        if (r < M) {
            float4 o;
            o.x = acc[i][0] + bv.x;
            o.y = acc[i][1] + bv.y;
            o.z = acc[i][2] + bv.z;
            o.w = acc[i][3] + bv.w;
            *(float4*)&C[(size_t)r * HC + (bn + (tx << 2))] = o;
        }
    }
}

// ---------------- Fused per-node edge attention + aggregation ----------------
// One wave per node. lane = h*16 + q; lane owns channels [4q..4q+3] of head h,
// i.e. flat offset lane*4 into the H*C=256 vector. Self-loop attr mean is
// accumulated in-register over the edge loop (no global deg/lsum needed).
__global__ __launch_bounds__(256) void gat_edge(
    const float* __restrict__ xl, const float* __restrict__ xr,
    const float4* __restrict__ csr, const int* __restrict__ row_start,
    const float* __restrict__ att, const float* __restrict__ We,
    const float* __restrict__ bias, float* __restrict__ out)
{
    const int lane = threadIdx.x & 63;
    const int node = (blockIdx.x * 256 + threadIdx.x) >> 6;
    if (node >= NN) return;
    const int j4 = lane << 2;

    const float4 xr4 = *(const float4*)&xr[(size_t)node * HC + j4];
    const float4 at4 = *(const float4*)&att[j4];
    const float4 w0  = *(const float4*)&We[j4];
    const float4 w1  = *(const float4*)&We[HC + j4];
    const float4 w2  = *(const float4*)&We[2 * HC + j4];

    float acc0 = 0.f, acc1 = 0.f, acc2 = 0.f, acc3 = 0.f, denom = 0.f;
    float eas0 = 0.f, eas1 = 0.f, eas2 = 0.f;    // running edge-attr sum (self-loop mean)
    const int beg = row_start[node], end = row_start[node + 1];

    float4 rec, xv;
    if (beg < end) {
        rec = csr[beg];
        xv  = *(const float4*)&xl[(size_t)__float_as_int(rec.x) * HC + j4];
    }
    for (int i = beg; i < end; i++) {
        float4 crec = rec, cxv = xv;
        if (i + 1 < end) {                        // 1-deep prefetch
            rec = csr[i + 1];
            xv  = *(const float4*)&xl[(size_t)__float_as_int(rec.x) * HC + j4];
        }
        float ea0 = crec.y, ea1 = crec.z, ea2 = crec.w;
        eas0 += ea0; eas1 += ea1; eas2 += ea2;
        float m0 = cxv.x + xr4.x + ea0 * w0.x + ea1 * w1.x + ea2 * w2.x;
        float m1 = cxv.y + xr4.y + ea0 * w0.y + ea1 * w1.y + ea2 * w2.y;
        float m2 = cxv.z + xr4.z + ea0 * w0.z + ea1 * w1.z + ea2 * w2.z;
        float m3 = cxv.w + xr4.w + ea0 * w0.w + ea1 * w1.w + ea2 * w2.w;
        m0 = (m0 > 0.f) ? m0 : NSLOPE * m0;
        m1 = (m1 > 0.f) ? m1 : NSLOPE * m1;
        m2 = (m2 > 0.f) ? m2 : NSLOPE * m2;
        m3 = (m3 > 0.f) ? m3 : NSLOPE * m3;
        float p = m0 * at4.x + m1 * at4.y + m2 * at4.z + m3 * at4.w;
        p += __shfl_xor(p, 1);
        p += __shfl_xor(p, 2);
        p += __shfl_xor(p, 4);
        p += __shfl_xor(p, 8);
        // softmax is shift-invariant; alpha is O(1) so no max subtraction needed
        float ex = expf(p);
        denom += ex;
        acc0 = fmaf(ex, cxv.x, acc0);
        acc1 = fmaf(ex, cxv.y, acc1);
        acc2 = fmaf(ex, cxv.z, acc2);
        acc3 = fmaf(ex, cxv.w, acc3);
    }

    {   // self loop: attr = mean of incoming edge attrs (0 if none)
        float rd = 1.0f / fmaxf((float)(end - beg), 1.0f);
        float ea0 = eas0 * rd, ea1 = eas1 * rd, ea2 = eas2 * rd;
        float4 sv = *(const float4*)&xl[(size_t)node * HC + j4];
        float m0 = sv.x + xr4.x + ea0 * w0.x + ea1 * w1.x + ea2 * w2.x;
        float m1 = sv.y + xr4.y + ea0 * w0.y + ea1 * w1.y + ea2 * w2.y;
        float m2 = sv.z + xr4.z + ea0 * w0.z + ea1 * w1.z + ea2 * w2.z;
        float m3 = sv.w + xr4.w + ea0 * w0.w + ea1 * w1.w + ea2 * w2.w;
        m0 = (m0 > 0.f) ? m0 : NSLOPE * m0;
        m1 = (m1 > 0.f) ? m1 : NSLOPE * m1;
        m2 = (m2 > 0.f) ? m2 : NSLOPE * m2;
        m3 = (m3 > 0.f) ? m3 : NSLOPE * m3;
        float p = m0 * at4.x + m1 * at4.y + m2 * at4.z + m3 * at4.w;
        p += __shfl_xor(p, 1);
        p += __shfl_xor(p, 2);
        p += __shfl_xor(p, 4);
        p += __shfl_xor(p, 8);
        float ex = expf(p);
        denom += ex;
        acc0 = fmaf(ex, sv.x, acc0);
        acc1 = fmaf(ex, sv.y, acc1);
        acc2 = fmaf(ex, sv.z, acc2);
        acc3 = fmaf(ex, sv.w, acc3);
    }

    const float inv = 1.0f / denom;
    float r0 = acc0 * inv, r1 = acc1 * inv, r2 = acc2 * inv, r3 = acc3 * inv;
    // head mean: lanes l, l+16, l+32, l+48 hold heads 0..3 of the same channels
    r0 += __shfl_xor(r0, 16); r0 += __shfl_xor(r0, 32);
    r1 += __shfl_xor(r1, 16); r1 += __shfl_xor(r1, 32);
    r2 += __shfl_xor(r2, 16); r2 += __shfl_xor(r2, 32);
    r3 += __shfl_xor(r3, 16); r3 += __shfl_xor(r3, 32);
    if (lane < 16) {
        float4 bv = *(const float4*)&bias[j4];
        float4 o;
        o.x = fmaxf(0.25f * r0 + bv.x, 0.f);   // mean over H=4 heads, +bias, ReLU
        o.y = fmaxf(0.25f * r1 + bv.y, 0.f);
        o.z = fmaxf(0.25f * r2 + bv.z, 0.f);
        o.w = fmaxf(0.25f * r3 + bv.w, 0.f);
        *(float4*)&out[(size_t)node * 64 + j4] = o;
    }
}

// ---------------- final linear: out[N x 32] = h[N x 64] @ Wmu + bmu ----------------
__global__ __launch_bounds__(256) void mu_kernel(
    const float* __restrict__ h, const float* __restrict__ Wmu,
    const float* __restrict__ bmu, float* __restrict__ out)
{
    __shared__ float ws[64 * 32];
    __shared__ float hs[8 * 64];
    const int tid = threadIdx.x;
#pragma unroll
    for (int i = 0; i < 8; i++) ws[tid + i * 256] = Wmu[tid + i * 256];
    const int nb = blockIdx.x * 8;   // 8 nodes/block, NN % 8 == 0
    {
        int idx = tid * 2;
        *(float2*)&hs[idx] = *(const float2*)&h[(size_t)nb * 64 + idx];
    }
    __syncthreads();
    const int ln = tid >> 5;     // 0..7
    const int o  = tid & 31;
    float acc = bmu[o];
#pragma unroll
    for (int k = 0; k < 64; k++) acc = fmaf(hs[ln * 64 + k], ws[k * 32 + o], acc);
    out[(size_t)(nb + ln) * 32 + o] = acc;
}

// ---------------- launch ----------------
extern "C" void kernel_launch(void* const* d_in, const int* in_sizes, int n_in,
                              void* d_out, int out_size, void* d_ws, size_t ws_size,
                              hipStream_t stream) {
    const float* x    = (const float*)d_in[0];
    const int*   ei   = (const int*)  d_in[1];
    const float* ea   = (const float*)d_in[2];
    const float* Wl0  = (const float*)d_in[3];
    const float* bl0  = (const float*)d_in[4];
    const float* Wr0  = (const float*)d_in[5];
    const float* br0  = (const float*)d_in[6];
    const float* We0  = (const float*)d_in[7];
    const float* att0 = (const float*)d_in[8];
    const float* bi0  = (const float*)d_in[9];
    const float* Wl1  = (const float*)d_in[10];
    const float* bl1  = (const float*)d_in[11];
    const float* Wr1  = (const float*)d_in[12];
    const float* br1  = (const float*)d_in[13];
    const float* We1  = (const float*)d_in[14];
    const float* att1 = (const float*)d_in[15];
    const float* bi1  = (const float*)d_in[16];
    const float* Wmu  = (const float*)d_in[17];
    const float* bmu  = (const float*)d_in[18];
    float* out = (float*)d_out;

    // workspace carve-up
    float* xl   = (float*)d_ws;                       // NN*256
    float* xr   = xl + (size_t)NN * HC;               // NN*256
    float* h1   = xr + (size_t)NN * HC;               // NN*64
    int*   deg  = (int*)(h1 + (size_t)NN * 64);       // NN
    int*   rows = deg + NN;                           // NN+1
    int*   curs = rows + NN + 1;                      // NN
    uintptr_t p = (uintptr_t)(curs + NN);
    p = (p + 255) & ~(uintptr_t)255;
    float4* csr = (float4*)p;                         // EE records

    // CSR build (edge_index/edge_attr shared by both layers)
    hipMemsetAsync(deg, 0, NN * sizeof(int), stream);
    deg_kernel<<<(EE / 4 + 255) / 256, 256, 0, stream>>>(ei + EE, deg);
    scan_kernel<<<1, 1024, 0, stream>>>(deg, rows, curs);
    scatter_kernel<<<(EE / 4 + 255) / 256, 256, 0, stream>>>(ei, ea, curs, csr);

    dim3 gg(4, (NN + 63) / 64);
    const int gat_grid = (NN * 64) / 256;   // one wave per node

    // layer 0
    gemm_bias_256<<<gg, 256, 0, stream>>>(x, Wl0, bl0, xl, NN, 256);
    gemm_bias_256<<<gg, 256, 0, stream>>>(x, Wr0, br0, xr, NN, 256);
    gat_edge<<<gat_grid, 256, 0, stream>>>(xl, xr, csr, rows, att0, We0, bi0, h1);

    // layer 1 (xl/xr buffers reused)
    gemm_bias_256<<<gg, 256, 0, stream>>>(h1, Wl1, bl1, xl, NN, 64);
    gemm_bias_256<<<gg, 256, 0, stream>>>(h1, Wr1, br1, xr, NN, 64);
    gat_edge<<<gat_grid, 256, 0, stream>>>(xl, xr, csr, rows, att1, We1, bi1, h1);

    // head
    mu_kernel<<<NN / 8, 256, 0, stream>>>(h1, Wmu, bmu, out);
}

// Round 3
// 721.324 us; speedup vs baseline: 1.3458x; 1.1668x over previous
//
#include <hip/hip_runtime.h>

// GATv2 2-layer encoder. R3: GEMMs moved to split-bf16 MFMA (hh+hl+lh, fp32 acc),
// W pre-transposed+split once; gat_edge pipelined 3-deep rec / 2-deep gather.
// N=50000, E=800000, IN=256, H=4, C=64, LAT=32, ED=3.

#define NN  50000
#define EE  800000
#define HC  256     // H*C
#define NSLOPE 0.2f

typedef float f32x4 __attribute__((ext_vector_type(4)));
typedef short bf16x8 __attribute__((ext_vector_type(8)));

__device__ __forceinline__ unsigned short f2b(float f) {   // fp32 -> bf16 RNE
    unsigned u = __float_as_uint(f);
    u += 0x7FFFu + ((u >> 16) & 1u);
    return (unsigned short)(u >> 16);
}
__device__ __forceinline__ float b2f(unsigned short h) {
    return __uint_as_float((unsigned)h << 16);
}

// ---------------- CSR build ----------------
__global__ __launch_bounds__(256) void deg_kernel(
    const int* __restrict__ dst, int* __restrict__ deg)
{
    int i = blockIdx.x * 256 + threadIdx.x;      // one int4 (4 edges) per thread
    if (i >= EE / 4) return;
    int4 v = ((const int4*)dst)[i];
    atomicAdd(&deg[v.x], 1);
    atomicAdd(&deg[v.y], 1);
    atomicAdd(&deg[v.z], 1);
    atomicAdd(&deg[v.w], 1);
}

__global__ __launch_bounds__(1024) void scan_kernel(
    const int* __restrict__ deg, int* __restrict__ row_start, int* __restrict__ cursor)
{
    __shared__ int sums[1024];
    const int tid = threadIdx.x;
    const int CH = (NN + 1023) / 1024;           // 49
    int b = tid * CH, e = min(b + CH, NN);
    int s = 0;
    for (int i = b; i < e; i++) s += deg[i];
    sums[tid] = s;
    __syncthreads();
    for (int off = 1; off < 1024; off <<= 1) {
        int v = (tid >= off) ? sums[tid - off] : 0;
        __syncthreads();
        sums[tid] += v;
        __syncthreads();
    }
    int run = (tid == 0) ? 0 : sums[tid - 1];
    for (int i = b; i < e; i++) {
        row_start[i] = run;
        cursor[i]    = run;
        run += deg[i];
    }
    if (tid == 0) row_start[NN] = EE;
}

__global__ __launch_bounds__(256) void scatter_kernel(
    const int* __restrict__ ei, const float* __restrict__ ea,
    int* __restrict__ cursor, float4* __restrict__ csr)
{
    int i = blockIdx.x * 256 + threadIdx.x;      // 4 edges per thread
    if (i >= EE / 4) return;
    int4 s = ((const int4*)ei)[i];
    int4 d = ((const int4*)(ei + EE))[i];
    float4 e0 = ((const float4*)ea)[i * 3 + 0];
    float4 e1 = ((const float4*)ea)[i * 3 + 1];
    float4 e2 = ((const float4*)ea)[i * 3 + 2];
    int p0 = atomicAdd(&cursor[d.x], 1);
    int p1 = atomicAdd(&cursor[d.y], 1);
    int p2 = atomicAdd(&cursor[d.z], 1);
    int p3 = atomicAdd(&cursor[d.w], 1);
    csr[p0] = make_float4(__int_as_float(s.x), e0.x, e0.y, e0.z);
    csr[p1] = make_float4(__int_as_float(s.y), e0.w, e1.x, e1.y);
    csr[p2] = make_float4(__int_as_float(s.z), e1.z, e1.w, e2.x);
    csr[p3] = make_float4(__int_as_float(s.w), e2.y, e2.z, e2.w);
}

// ---------------- W -> W^T split (bf16 hi/lo planes), once per weight ----------------
__global__ __launch_bounds__(256) void cvt_wt(
    const float* __restrict__ W, unsigned short* __restrict__ WTh,
    unsigned short* __restrict__ WTl, int K)
{
    int i = blockIdx.x * 256 + threadIdx.x;
    if (i >= K * 256) return;
    int k = i >> 8, c = i & 255;
    float v = W[i];
    unsigned short h = f2b(v);
    unsigned short l = f2b(v - b2f(h));
    WTh[(size_t)c * K + k] = h;
    WTl[(size_t)c * K + k] = l;
}

// ---------------- split-bf16 MFMA GEMM: C[MxHC] = A[MxK] @ W[KxHC] + bias ----------
// A fp32 (split hi/lo on the fly during staging); B given as W^T bf16 planes.
// Block tile 64x128, 4 waves each 32x64 (2x4 MFMA tiles of 16x16), 3 products/tile.
__global__ __launch_bounds__(256) void gemm_mfma(
    const float* __restrict__ A,
    const unsigned short* __restrict__ BTh, const unsigned short* __restrict__ BTl,
    const float* __restrict__ bias, float* __restrict__ C,
    int M, int K)
{
    __shared__ unsigned short Ah[64][40], Al[64][40];     // +8 pad: bank spread
    __shared__ unsigned short Bh[128][40], Bl[128][40];
    const int tid = threadIdx.x;
    const int bm = blockIdx.y << 6;
    const int bn = blockIdx.x << 7;
    const int w  = tid >> 6, l = tid & 63;
    const int wr = w >> 1, wc = w & 1;
    const int lr = l & 15, lk = l >> 4;

    f32x4 acc[2][4];
#pragma unroll
    for (int a = 0; a < 2; a++)
#pragma unroll
        for (int b = 0; b < 4; b++) acc[a][b] = (f32x4){0.f, 0.f, 0.f, 0.f};

    const int ar = tid >> 2, ac = (tid & 3) << 3;   // A stage: row 0..63, k-chunk {0,8,16,24}

    for (int k0 = 0; k0 < K; k0 += 32) {
        // ---- stage A (fp32 -> bf16 hi/lo split in registers) ----
        float av[8];
        if (bm + ar < M) {
            *(float4*)&av[0] = *(const float4*)&A[(size_t)(bm + ar) * K + k0 + ac];
            *(float4*)&av[4] = *(const float4*)&A[(size_t)(bm + ar) * K + k0 + ac + 4];
        } else {
#pragma unroll
            for (int j = 0; j < 8; j++) av[j] = 0.f;
        }
        unsigned hp[4], lp[4];
#pragma unroll
        for (int j = 0; j < 4; j++) {
            unsigned short h0 = f2b(av[2 * j]),     h1 = f2b(av[2 * j + 1]);
            unsigned short l0 = f2b(av[2 * j]     - b2f(h0));
            unsigned short l1 = f2b(av[2 * j + 1] - b2f(h1));
            hp[j] = (unsigned)h0 | ((unsigned)h1 << 16);
            lp[j] = (unsigned)l0 | ((unsigned)l1 << 16);
        }
        *(uint4*)&Ah[ar][ac] = make_uint4(hp[0], hp[1], hp[2], hp[3]);
        *(uint4*)&Al[ar][ac] = make_uint4(lp[0], lp[1], lp[2], lp[3]);
        // ---- stage B (bf16 planes, direct copy) ----
#pragma unroll
        for (int rep = 0; rep < 2; rep++) {
            int idx = tid + (rep << 8);              // 0..511
            int rb = idx >> 2, cb = (idx & 3) << 3;
            *(uint4*)&Bh[rb][cb] = *(const uint4*)&BTh[(size_t)(bn + rb) * K + k0 + cb];
            *(uint4*)&Bl[rb][cb] = *(const uint4*)&BTl[(size_t)(bn + rb) * K + k0 + cb];
        }
        __syncthreads();

        bf16x8 afh[2], afl[2], bfh[4], bfl[4];
#pragma unroll
        for (int a = 0; a < 2; a++) {
            afh[a] = *(const bf16x8*)&Ah[wr * 32 + a * 16 + lr][lk << 3];
            afl[a] = *(const bf16x8*)&Al[wr * 32 + a * 16 + lr][lk << 3];
        }
#pragma unroll
        for (int b = 0; b < 4; b++) {
            bfh[b] = *(const bf16x8*)&Bh[wc * 64 + b * 16 + lr][lk << 3];
            bfl[b] = *(const bf16x8*)&Bl[wc * 64 + b * 16 + lr][lk << 3];
        }
#pragma unroll
        for (int a = 0; a < 2; a++)
#pragma unroll
            for (int b = 0; b < 4; b++) {
                acc[a][b] = __builtin_amdgcn_mfma_f32_16x16x32_bf16(afh[a], bfh[b], acc[a][b], 0, 0, 0);
                acc[a][b] = __builtin_amdgcn_mfma_f32_16x16x32_bf16(afh[a], bfl[b], acc[a][b], 0, 0, 0);
                acc[a][b] = __builtin_amdgcn_mfma_f32_16x16x32_bf16(afl[a], bfh[b], acc[a][b], 0, 0, 0);
            }
        __syncthreads();
    }

    // epilogue: D row=(lane>>4)*4+i, col=lane&15 within each 16x16 tile
#pragma unroll
    for (int a = 0; a < 2; a++) {
        int rbase = bm + wr * 32 + a * 16 + (lk << 2);
#pragma unroll
        for (int b = 0; b < 4; b++) {
            int cg = bn + wc * 64 + b * 16 + lr;
            float bs = bias[cg];
#pragma unroll
            for (int i = 0; i < 4; i++) {
                int rg = rbase + i;
                if (rg < M) C[(size_t)rg * HC + cg] = acc[a][b][i] + bs;
            }
        }
    }
}

// ---------------- Fused per-node edge attention + aggregation ----------------
// One wave per node. lane = h*16 + q; lane owns channels [4q..4q+3] of head h.
// rec pipeline 3-deep, xl-gather pipeline 2-deep (~2 iters of latency cover).
__global__ __launch_bounds__(256) void gat_edge(
    const float* __restrict__ xl, const float* __restrict__ xr,
    const float4* __restrict__ csr, const int* __restrict__ row_start,
    const float* __restrict__ att, const float* __restrict__ We,
    const float* __restrict__ bias, float* __restrict__ out)
{
    const int lane = threadIdx.x & 63;
    const int node = (blockIdx.x * 256 + threadIdx.x) >> 6;
    if (node >= NN) return;
    const int j4 = lane << 2;
    const float4* xlv = (const float4*)xl;     // node row = 64 float4s

    const float4 xr4 = *(const float4*)&xr[(size_t)node * HC + j4];
    const float4 at4 = *(const float4*)&att[j4];
    const float4 w0  = *(const float4*)&We[j4];
    const float4 w1  = *(const float4*)&We[HC + j4];
    const float4 w2  = *(const float4*)&We[2 * HC + j4];

    float acc0 = 0.f, acc1 = 0.f, acc2 = 0.f, acc3 = 0.f, denom = 0.f;
    float eas0 = 0.f, eas1 = 0.f, eas2 = 0.f;
    const int beg = row_start[node];
    const int n   = row_start[node + 1] - beg;
    const float4* cp = csr + beg;

    float4 r0 = {0,0,0,0}, r1 = {0,0,0,0}, r2 = {0,0,0,0};
    float4 v0 = {0,0,0,0}, v1 = {0,0,0,0};
    if (n > 0) { r0 = cp[0]; v0 = xlv[(size_t)__float_as_int(r0.x) * 64 + lane]; }
    if (n > 1) { r1 = cp[1]; v1 = xlv[(size_t)__float_as_int(r1.x) * 64 + lane]; }
    if (n > 2) { r2 = cp[2]; }

    for (int i = 0; i < n; i++) {
        float4 crec = r0, cxv = v0;
        r0 = r1; r1 = r2; v0 = v1;
        if (i + 3 < n) r2 = cp[i + 3];
        if (i + 2 < n) v1 = xlv[(size_t)__float_as_int(r1.x) * 64 + lane];

        float ea0 = crec.y, ea1 = crec.z, ea2 = crec.w;
        eas0 += ea0; eas1 += ea1; eas2 += ea2;
        float m0 = cxv.x + xr4.x + ea0 * w0.x + ea1 * w1.x + ea2 * w2.x;
        float m1 = cxv.y + xr4.y + ea0 * w0.y + ea1 * w1.y + ea2 * w2.y;
        float m2 = cxv.z + xr4.z + ea0 * w0.z + ea1 * w1.z + ea2 * w2.z;
        float m3 = cxv.w + xr4.w + ea0 * w0.w + ea1 * w1.w + ea2 * w2.w;
        m0 = fmaxf(m0, NSLOPE * m0);           // leaky-relu as single v_max
        m1 = fmaxf(m1, NSLOPE * m1);
        m2 = fmaxf(m2, NSLOPE * m2);
        m3 = fmaxf(m3, NSLOPE * m3);
        float p = m0 * at4.x + m1 * at4.y + m2 * at4.z + m3 * at4.w;
        p += __shfl_xor(p, 1);
        p += __shfl_xor(p, 2);
        p += __shfl_xor(p, 4);
        p += __shfl_xor(p, 8);
        // softmax shift-invariant; alpha O(1) so no max subtraction needed
        float ex = __expf(p);
        denom += ex;
        acc0 = fmaf(ex, cxv.x, acc0);
        acc1 = fmaf(ex, cxv.y, acc1);
        acc2 = fmaf(ex, cxv.z, acc2);
        acc3 = fmaf(ex, cxv.w, acc3);
    }

    {   // self loop: attr = mean of incoming edge attrs (0 if none)
        float rd = 1.0f / fmaxf((float)n, 1.0f);
        float ea0 = eas0 * rd, ea1 = eas1 * rd, ea2 = eas2 * rd;
        float4 sv = xlv[(size_t)node * 64 + lane];
        float m0 = sv.x + xr4.x + ea0 * w0.x + ea1 * w1.x + ea2 * w2.x;
        float m1 = sv.y + xr4.y + ea0 * w0.y + ea1 * w1.y + ea2 * w2.y;
        float m2 = sv.z + xr4.z + ea0 * w0.z + ea1 * w1.z + ea2 * w2.z;
        float m3 = sv.w + xr4.w + ea0 * w0.w + ea1 * w1.w + ea2 * w2.w;
        m0 = fmaxf(m0, NSLOPE * m0);
        m1 = fmaxf(m1, NSLOPE * m1);
        m2 = fmaxf(m2, NSLOPE * m2);
        m3 = fmaxf(m3, NSLOPE * m3);
        float p = m0 * at4.x + m1 * at4.y + m2 * at4.z + m3 * at4.w;
        p += __shfl_xor(p, 1);
        p += __shfl_xor(p, 2);
        p += __shfl_xor(p, 4);
        p += __shfl_xor(p, 8);
        float ex = __expf(p);
        denom += ex;
        acc0 = fmaf(ex, sv.x, acc0);
        acc1 = fmaf(ex, sv.y, acc1);
        acc2 = fmaf(ex, sv.z, acc2);
        acc3 = fmaf(ex, sv.w, acc3);
    }

    const float inv = 1.0f / denom;
    float r0s = acc0 * inv, r1s = acc1 * inv, r2s = acc2 * inv, r3s = acc3 * inv;
    // head mean: lanes l, l+16, l+32, l+48 hold heads 0..3 of the same channels
    r0s += __shfl_xor(r0s, 16); r0s += __shfl_xor(r0s, 32);
    r1s += __shfl_xor(r1s, 16); r1s += __shfl_xor(r1s, 32);
    r2s += __shfl_xor(r2s, 16); r2s += __shfl_xor(r2s, 32);
    r3s += __shfl_xor(r3s, 16); r3s += __shfl_xor(r3s, 32);
    if (lane < 16) {
        float4 bv = *(const float4*)&bias[j4];
        float4 o;
        o.x = fmaxf(0.25f * r0s + bv.x, 0.f);   // mean over H=4 heads, +bias, ReLU
        o.y = fmaxf(0.25f * r1s + bv.y, 0.f);
        o.z = fmaxf(0.25f * r2s + bv.z, 0.f);
        o.w = fmaxf(0.25f * r3s + bv.w, 0.f);
        *(float4*)&out[(size_t)node * 64 + j4] = o;
    }
}

// ---------------- final linear: out[N x 32] = h[N x 64] @ Wmu + bmu ----------------
__global__ __launch_bounds__(256) void mu_kernel(
    const float* __restrict__ h, const float* __restrict__ Wmu,
    const float* __restrict__ bmu, float* __restrict__ out)
{
    __shared__ float ws[64 * 32];
    __shared__ float hs[8 * 64];
    const int tid = threadIdx.x;
#pragma unroll
    for (int i = 0; i < 8; i++) ws[tid + i * 256] = Wmu[tid + i * 256];
    const int nb = blockIdx.x * 8;   // 8 nodes/block, NN % 8 == 0
    {
        int idx = tid * 2;
        *(float2*)&hs[idx] = *(const float2*)&h[(size_t)nb * 64 + idx];
    }
    __syncthreads();
    const int ln = tid >> 5;     // 0..7
    const int o  = tid & 31;
    float acc = bmu[o];
#pragma unroll
    for (int k = 0; k < 64; k++) acc = fmaf(hs[ln * 64 + k], ws[k * 32 + o], acc);
    out[(size_t)(nb + ln) * 32 + o] = acc;
}

// ---------------- launch ----------------
extern "C" void kernel_launch(void* const* d_in, const int* in_sizes, int n_in,
                              void* d_out, int out_size, void* d_ws, size_t ws_size,
                              hipStream_t stream) {
    const float* x    = (const float*)d_in[0];
    const int*   ei   = (const int*)  d_in[1];
    const float* ea   = (const float*)d_in[2];
    const float* Wl0  = (const float*)d_in[3];
    const float* bl0  = (const float*)d_in[4];
    const float* Wr0  = (const float*)d_in[5];
    const float* br0  = (const float*)d_in[6];
    const float* We0  = (const float*)d_in[7];
    const float* att0 = (const float*)d_in[8];
    const float* bi0  = (const float*)d_in[9];
    const float* Wl1  = (const float*)d_in[10];
    const float* bl1  = (const float*)d_in[11];
    const float* Wr1  = (const float*)d_in[12];
    const float* br1  = (const float*)d_in[13];
    const float* We1  = (const float*)d_in[14];
    const float* att1 = (const float*)d_in[15];
    const float* bi1  = (const float*)d_in[16];
    const float* Wmu  = (const float*)d_in[17];
    const float* bmu  = (const float*)d_in[18];
    float* out = (float*)d_out;

    // workspace carve-up (~129.3 MB total, same footprint as proven R1/R2)
    float* xl32 = (float*)d_ws;                        // NN*256
    float* xr32 = xl32 + (size_t)NN * HC;              // NN*256
    float* h1   = xr32 + (size_t)NN * HC;              // NN*64
    int*   deg  = (int*)(h1 + (size_t)NN * 64);        // NN
    int*   rows = deg + NN;                            // NN+1
    int*   curs = rows + NN + 1;                       // NN
    uintptr_t p = (uintptr_t)(curs + NN);
    p = (p + 15) & ~(uintptr_t)15;
    unsigned short* wt = (unsigned short*)p;
    unsigned short* Wl0Th = wt;                  unsigned short* Wl0Tl = wt + 65536;
    unsigned short* Wr0Th = wt + 65536 * 2;      unsigned short* Wr0Tl = wt + 65536 * 3;
    unsigned short* Wl1Th = wt + 65536 * 4;      unsigned short* Wl1Tl = Wl1Th + 16384;
    unsigned short* Wr1Th = Wl1Th + 16384 * 2;   unsigned short* Wr1Tl = Wl1Th + 16384 * 3;
    p = (uintptr_t)(Wl1Th + 16384 * 4);
    p = (p + 255) & ~(uintptr_t)255;
    float4* csr = (float4*)p;                          // EE records

    // CSR build (shared by both layers)
    hipMemsetAsync(deg, 0, NN * sizeof(int), stream);
    deg_kernel<<<(EE / 4 + 255) / 256, 256, 0, stream>>>(ei + EE, deg);
    scan_kernel<<<1, 1024, 0, stream>>>(deg, rows, curs);
    scatter_kernel<<<(EE / 4 + 255) / 256, 256, 0, stream>>>(ei, ea, curs, csr);

    // weight transpose+split (tiny, once)
    cvt_wt<<<256, 256, 0, stream>>>(Wl0, Wl0Th, Wl0Tl, 256);
    cvt_wt<<<256, 256, 0, stream>>>(Wr0, Wr0Th, Wr0Tl, 256);
    cvt_wt<<< 64, 256, 0, stream>>>(Wl1, Wl1Th, Wl1Tl, 64);
    cvt_wt<<< 64, 256, 0, stream>>>(Wr1, Wr1Th, Wr1Tl, 64);

    dim3 gg(2, (NN + 63) / 64);
    const int gat_grid = (NN * 64) / 256;   // one wave per node

    // layer 0
    gemm_mfma<<<gg, 256, 0, stream>>>(x, Wl0Th, Wl0Tl, bl0, xl32, NN, 256);
    gemm_mfma<<<gg, 256, 0, stream>>>(x, Wr0Th, Wr0Tl, br0, xr32, NN, 256);
    gat_edge<<<gat_grid, 256, 0, stream>>>(xl32, xr32, csr, rows, att0, We0, bi0, h1);

    // layer 1
    gemm_mfma<<<gg, 256, 0, stream>>>(h1, Wl1Th, Wl1Tl, bl1, xl32, NN, 64);
    gemm_mfma<<<gg, 256, 0, stream>>>(h1, Wr1Th, Wr1Tl, br1, xr32, NN, 64);
    gat_edge<<<gat_grid, 256, 0, stream>>>(xl32, xr32, csr, rows, att1, We1, bi1, h1);

    // head
    mu_kernel<<<NN / 8, 256, 0, stream>>>(h1, Wmu, bmu, out);
}